// Round 8
// baseline (606.604 us; speedup 1.0000x reference)
//
#include <hip/hip_runtime.h>

#define HSZ 50        // hidden units
#define TSZ 512       // timesteps
#define NROW 200      // 4*HSZ gate rows, flattened on MFMA m
#define MT   13       // m-tiles of 16 (208 rows, 8 zero pad rows)
#define KAUG 64       // augmented K: h[0..49], 1.0 at 50, x_t at 51, 0 pad

typedef _Float16 half8   __attribute__((ext_vector_type(8)));
typedef float    floatx4 __attribute__((ext_vector_type(4)));

// sigmoid/tanh via exp+rcp, robust at extremes (proven R4-R7, absmax 9.8e-4)
__device__ __forceinline__ float fast_sig(float x) {
    return __builtin_amdgcn_rcpf(1.0f + __expf(-x));
}
__device__ __forceinline__ float fast_tanh(float x) {
    return fmaf(-2.0f, __builtin_amdgcn_rcpf(1.0f + __expf(2.0f * x)), 1.0f);
}

// One wave per batch element, ZERO barriers (every LDS buffer is wave-private;
// a wave's own LDS ops complete in order with s_waitcnt only). The recurrent
// matvec is 26 mfma_f32_16x16x32_f16 over a flattened 200-row A = [W_hh | bias
// | W_ih] with K augmented by h[50]=1, h[51]=x_t -- so the MFMA C-input is a
// loop-invariant zero and there is no per-step bias/x projection at all.
// B is h broadcast-replicated across all 16 columns from a 128-B LDS line.
// C->activation repack: 13 masked b128 stores (lanes n==0), then lane j reads
// unit j's 4 gate preacts (rows j, j+50, j+100, j+150) -> 10 trans per step,
// lane-local c/h state. 2048 waves = 2 waves/SIMD hides the LDS/MFMA latency.
__global__ __launch_bounds__(256) __attribute__((amdgpu_waves_per_eu(2, 2)))
void lstm_wave(const float* __restrict__ x,
               const float* __restrict__ W_ih,
               const float* __restrict__ W_hh,
               const float* __restrict__ b_ih,
               const float* __restrict__ b_hh,
               const float* __restrict__ W_lin,
               const float* __restrict__ b_lin,
               float* __restrict__ out)
{
    // Per-wave private regions (indexed by wave id w; no cross-wave access).
    __shared__ float    xs[4][TSZ];        // this wave's x stream   (8 KB)
    __shared__ float    gl[4][MT * 16];    // gate preacts, row-major (3.25 KB)
    __shared__ __align__(16) _Float16 hb[4][KAUG];  // augmented h     (0.5 KB)

    const int tid = threadIdx.x;
    const int w   = tid >> 6;         // wave id in block (0..3)
    const int j   = tid & 63;         // lane
    const int n   = j & 15;           // MFMA col / A-row offset
    const int q   = j >> 4;           // quad (k-group)
    const int b   = blockIdx.x * 4 + w;

    // --- stage this wave's x (contiguous 512 floats, coalesced) ---
    const float* xg = x + (size_t)b * TSZ;
    for (int i = j; i < TSZ; i += 64)
        xs[w][i] = xg[i];

    // --- init augmented h line: h=0, slot 50 = 1.0, rest 0 ---
    hb[w][j] = (j == 50) ? (_Float16)1.0f : (_Float16)0.0f;

    // --- static A fragments: lane holds A[row=16*mt+n][k=kt*32+q*8+jj] ---
    // A[row][k<50] = W_hh[row][k]; A[row][50] = b_ih+b_hh; A[row][51] = W_ih.
    half8 af[MT][2];
#pragma unroll
    for (int mt = 0; mt < MT; ++mt) {
        const int row = 16 * mt + n;
        const bool rok = (row < NROW);
#pragma unroll
        for (int kt = 0; kt < 2; ++kt) {
#pragma unroll
            for (int jj = 0; jj < 8; ++jj) {
                const int k = kt * 32 + q * 8 + jj;
                float v = 0.0f;
                if (rok) {
                    if (k < HSZ)        v = W_hh[row * HSZ + k];
                    else if (k == 50)   v = b_ih[row] + b_hh[row];
                    else if (k == 51)   v = W_ih[row];
                }
                af[mt][kt][jj] = (_Float16)v;
            }
        }
    }

    const floatx4 zero4 = {0.0f, 0.0f, 0.0f, 0.0f};
    float h = 0.0f, c = 0.0f;
    float xv = xs[w][0];              // wave-private LDS, in-order: no barrier

#pragma unroll 1
    for (int t = 0; t < TSZ; ++t) {
        // Publish h (lanes 0..49) and x_t (lane 51) into the augmented line.
        const _Float16 pub = (j < HSZ) ? (_Float16)h : (_Float16)xv;
        if (j < HSZ || j == 51)
            hb[w][j] = pub;

        // B fragments: h replicated to all 16 cols -> broadcast b128 reads.
        const half8 bf0 = *(const half8*)&hb[w][q * 8];
        const half8 bf1 = *(const half8*)&hb[w][32 + q * 8];

        // 13 independent 2-deep MFMA chains; C starts at zero (bias via K-aug).
        floatx4 acc[MT];
#pragma unroll
        for (int mt = 0; mt < MT; ++mt) {
            acc[mt] = __builtin_amdgcn_mfma_f32_16x16x32_f16(af[mt][0], bf0, zero4,   0, 0, 0);
            acc[mt] = __builtin_amdgcn_mfma_f32_16x16x32_f16(af[mt][1], bf1, acc[mt], 0, 0, 0);
        }

        // Repack C -> row-major gate buffer: col 0 lanes store rows 16mt+4q+r.
        if (n == 0) {
#pragma unroll
            for (int mt = 0; mt < MT; ++mt)
                *(floatx4*)&gl[w][16 * mt + 4 * q] = acc[mt];
        }

        // Prefetch next x (independent, issues alongside the gate reads).
        const float xnext = xs[w][(t + 1) & (TSZ - 1)];

        // Lane j owns unit j: read its 4 gate preacts (consecutive addrs ->
        // 2 lanes/bank = conflict-free), then 10 trans, lane-local state.
        const int u = (j < HSZ) ? j : 0;
        const float pi = gl[w][u];
        const float pf = gl[w][u + 50];
        const float pg = gl[w][u + 100];
        const float po = gl[w][u + 150];

        const float gi = fast_sig (pi);
        const float gf = fast_sig (pf);
        const float gg = fast_tanh(pg);
        const float go = fast_sig (po);
        c = fmaf(gf, c, gi * gg);
        h = go * fast_tanh(c);
        xv = xnext;
    }

    // --- epilogue: out[b] = dot(h_T, W_lin) + b_lin ---
    const float wl = (j < HSZ) ? W_lin[j] : 0.0f;
    float p = ((j < HSZ) ? h : 0.0f) * wl;
#pragma unroll
    for (int off = 32; off > 0; off >>= 1)
        p += __shfl_down(p, off, 64);
    if (j == 0) out[b] = p + b_lin[0];
}

extern "C" void kernel_launch(void* const* d_in, const int* in_sizes, int n_in,
                              void* d_out, int out_size, void* d_ws, size_t ws_size,
                              hipStream_t stream) {
    const float* x     = (const float*)d_in[0];
    const float* W_ih  = (const float*)d_in[1];
    const float* W_hh  = (const float*)d_in[2];
    const float* b_ih  = (const float*)d_in[3];
    const float* b_hh  = (const float*)d_in[4];
    const float* W_lin = (const float*)d_in[5];
    const float* b_lin = (const float*)d_in[6];
    float* outp = (float*)d_out;

    const int B = in_sizes[0] / TSZ;   // 2048 -> 512 blocks x 4 waves
    hipLaunchKernelGGL(lstm_wave, dim3(B / 4), dim3(256), 0, stream,
                       x, W_ih, W_hh, b_ih, b_hh, W_lin, b_lin, outp);
}

// Round 9
// 317.229 us; speedup vs baseline: 1.9122x; 1.9122x over previous
//
#include <hip/hip_runtime.h>

#define HSZ 50        // real hidden units
#define TSZ 512       // timesteps
#define NB  4         // batch tile per workgroup -> 512 wgs -> 2 wgs/CU
#define UW  16        // units per wave (4 waves x 16 = 64 padded units)
#define KPAD 72       // hlds u-stride in f16 (144 B rows, 16B-aligned)

typedef _Float16 half8   __attribute__((ext_vector_type(8)));
typedef float    floatx4 __attribute__((ext_vector_type(4)));

// sigmoid/tanh via exp+rcp, robust at extremes (proven R4-R8, absmax 9.8e-4)
__device__ __forceinline__ float fast_sig(float x) {
    return __builtin_amdgcn_rcpf(1.0f + __expf(-x));
}
__device__ __forceinline__ float fast_tanh(float x) {
    return fmaf(-2.0f, __builtin_amdgcn_rcpf(1.0f + __expf(2.0f * x)), 1.0f);
}

// Workgroup = 4 waves, 4-batch stream; 512 workgroups -> 2 co-resident wgs/CU
// (2 waves/SIMD) so the per-step chain latency of one wg hides under the
// other's issue. Wave w owns units [16w,16w+16): 8 mfma_f32_16x16x32_f16
// (B cols 4..15 are zero -- MFMA columns are cheap, trans issue is not).
// The wave then repacks its C through wave-private LDS (4 masked b128 stores
// + 4 b32 reads, NO barrier) so each of its 64 lanes owns exactly one
// (unit,batch) pair -> 10 trans/wave/step (R6 spent 320 cyc on 40 trans).
// h returns via the proven f16 h^T double buffer; 1 barrier/step total.
// Padded units (50..63) have zero weights/bias -> h stays exactly 0.
__global__ __launch_bounds__(256) __attribute__((amdgpu_waves_per_eu(2, 2)))
void lstm_mfma4(const float* __restrict__ x,
                const float* __restrict__ W_ih,
                const float* __restrict__ W_hh,
                const float* __restrict__ b_ih,
                const float* __restrict__ b_hh,
                const float* __restrict__ W_lin,
                const float* __restrict__ b_lin,
                float* __restrict__ out)
{
    __shared__ float xs[TSZ][NB];                         // x^T [t][n]  (8 KB)
    __shared__ __align__(16) float glds[4][4][NB][UW];    // [w][g][n][u] (4 KB)
    __shared__ __align__(16) _Float16 hlds[2][16][KPAD];  // h^T dbuf   (4.5 KB)

    const int tid = threadIdx.x;
    const int w   = tid >> 6;        // wave id 0..3 -> unit group
    const int ln  = tid & 63;        // lane
    const int n   = ln & 15;         // MFMA column
    const int q   = ln >> 4;         // quad
    const int b0  = blockIdx.x * NB;

    // --- stage x transposed: global [b][t] -> LDS [t][b] (coalesced) ---
    const float* xg = x + (size_t)b0 * TSZ;
    for (int i = tid; i < NB * TSZ; i += 256)
        xs[i & (TSZ - 1)][i >> 9] = xg[i];
    // --- zero h buffers: h0 = 0; cols 4..15 and pad units stay 0 forever ---
    for (int i = tid; i < 2 * 16 * KPAD; i += 256)
        ((_Float16*)hlds)[i] = (_Float16)0.0f;

    // --- A fragments: lane holds A[m = 16w+n][k = kt*32 + q*8 + j] ---
    const int uA = 16 * w + n;
    half8 af[4][2];
#pragma unroll
    for (int g = 0; g < 4; ++g) {
#pragma unroll
        for (int kt = 0; kt < 2; ++kt) {
#pragma unroll
            for (int j = 0; j < 8; ++j) {
                const int k = kt * 32 + q * 8 + j;
                const float v = (uA < HSZ && k < HSZ)
                              ? W_hh[(g * HSZ + uA) * HSZ + k] : 0.0f;
                af[g][kt][j] = (_Float16)v;
            }
        }
    }
    // --- bias / W_ih for this lane's C rows (units ub..ub+3, 4 gates) ---
    const int ub = 16 * w + 4 * q;
    float biasr[4][4], wihr[4][4];
#pragma unroll
    for (int g = 0; g < 4; ++g) {
#pragma unroll
        for (int r = 0; r < 4; ++r) {
            const int u   = ub + r;
            const int row = g * HSZ + u;
            const bool ok = (u < HSZ);
            biasr[g][r] = ok ? (b_ih[row] + b_hh[row]) : 0.0f;
            wihr[g][r]  = ok ? W_ih[row] : 0.0f;
        }
    }

    // --- activation-role mapping: lane owns (batch na, unit 16w+ua) ---
    const int na = ln >> 4;          // 0..3
    const int ua = ln & 15;          // 0..15 within this wave's unit group
    float c = 0.0f;                  // lane-local cell state

    __syncthreads();                 // xs + hlds ready

#pragma unroll 2
    for (int t = 0; t < TSZ; ++t) {
        const int rb = t & 1, wb = rb ^ 1;

        // B fragments: hlds[rb][n][k-contiguous]; cols >=4 are always zero.
        const half8 bf0 = *(const half8*)&hlds[rb][n][q * 8];
        const half8 bf1 = *(const half8*)&hlds[rb][n][32 + q * 8];
        const float xv  = xs[t][n & 3];

        floatx4 acc[4];
#pragma unroll
        for (int g = 0; g < 4; ++g)
#pragma unroll
            for (int r = 0; r < 4; ++r)
                acc[g][r] = fmaf(xv, wihr[g][r], biasr[g][r]);
#pragma unroll
        for (int g = 0; g < 4; ++g) {
            acc[g] = __builtin_amdgcn_mfma_f32_16x16x32_f16(af[g][0], bf0, acc[g], 0, 0, 0);
            acc[g] = __builtin_amdgcn_mfma_f32_16x16x32_f16(af[g][1], bf1, acc[g], 0, 0, 0);
        }

        // Wave-private repack: cols n<4 are real batches. C rows ub..ub+3 are
        // contiguous -> one b128 store per gate (16 lanes, 2-way banks = free).
        if (n < 4) {
#pragma unroll
            for (int g = 0; g < 4; ++g)
                *(floatx4*)&glds[w][g][n][4 * q] = acc[g];
        }
        // Read back own (unit,batch): addr g*64 + ln -> stride-1, conflict-free.
        const float pi = glds[w][0][na][ua];
        const float pf = glds[w][1][na][ua];
        const float pg = glds[w][2][na][ua];
        const float po = glds[w][3][na][ua];

        // 10 trans, lane-local state. Pad units: all-zero gates -> h = 0.
        const float si = fast_sig (pi);
        const float sf = fast_sig (pf);
        const float sg = fast_tanh(pg);
        const float so = fast_sig (po);
        c = fmaf(sf, c, si * sg);
        const float h = so * fast_tanh(c);

        hlds[wb][na][16 * w + ua] = (_Float16)h;
        __syncthreads();             // h(t) visible for next step's B-read
    }

    // --- epilogue: out[b0+n'] = b_lin + sum_u h_T[u] * W_lin[u].
    //     TSZ even -> final h in buffer 0 (protected by the loop's last barrier).
    if (w == 0 && ln < NB) {
        float acc = b_lin[0];
        for (int u = 0; u < HSZ; ++u)
            acc = fmaf((float)hlds[0][ln][u], W_lin[u], acc);
        out[(size_t)b0 + ln] = acc;
    }
}

extern "C" void kernel_launch(void* const* d_in, const int* in_sizes, int n_in,
                              void* d_out, int out_size, void* d_ws, size_t ws_size,
                              hipStream_t stream) {
    const float* x     = (const float*)d_in[0];
    const float* W_ih  = (const float*)d_in[1];
    const float* W_hh  = (const float*)d_in[2];
    const float* b_ih  = (const float*)d_in[3];
    const float* b_hh  = (const float*)d_in[4];
    const float* W_lin = (const float*)d_in[5];
    const float* b_lin = (const float*)d_in[6];
    float* outp = (float*)d_out;

    const int B = in_sizes[0] / TSZ;   // 2048 -> 512 workgroups of 4 batches
    hipLaunchKernelGGL(lstm_mfma4, dim3(B / NB), dim3(256), 0, stream,
                       x, W_ih, W_hh, b_ih, b_hh, W_lin, b_lin, outp);
}

// Round 10
// 310.045 us; speedup vs baseline: 1.9565x; 1.0232x over previous
//
#include <hip/hip_runtime.h>

#define HSZ 50        // real hidden units
#define TSZ 512       // timesteps
#define NB  4         // batches per workgroup -> 512 wgs
#define KPAD 72       // hlds row stride in f16 (144 B, 16B-aligned)
#define GNS 260       // glds batch stride in dwords (u*4+g layout, +4 pad)

typedef _Float16 half8   __attribute__((ext_vector_type(8)));
typedef float    floatx4 __attribute__((ext_vector_type(4)));

// sigmoid/tanh via exp+rcp, robust at extremes (proven R4-R9, absmax ~1e-3)
__device__ __forceinline__ float fast_sig(float x) {
    return __builtin_amdgcn_rcpf(1.0f + __expf(-x));
}
__device__ __forceinline__ float fast_tanh(float x) {
    return fmaf(-2.0f, __builtin_amdgcn_rcpf(1.0f + __expf(2.0f * x)), 1.0f);
}

// R9 skeleton (4 waves x 4-batch stream, 1 barrier/step) with the chain cut:
// (1) K-augmentation: A gains columns k=50 (bias) and k=51 (W_ih); B rows
//     carry 1.0 at k=50 and x_t at k=51 -> MFMA C-input is literal zero, no
//     per-step acc-init fmas, no xs read on the chain.
// (2) gate repack relayout [n][u][g]: producer lane (q,n) writes b128s of
//     {i,f,g,o}(unit 4q+r); consumer lane reads its 4 gate preacts with ONE
//     ds_read_b128 (was 4x b32). Batch stride 260 dw -> 2-way write banks.
// (3) h-writes masked off k=50/51 so the augmentation slots survive.
__global__ __launch_bounds__(256) __attribute__((amdgpu_waves_per_eu(2, 2)))
void lstm_kaug(const float* __restrict__ x,
               const float* __restrict__ W_ih,
               const float* __restrict__ W_hh,
               const float* __restrict__ b_ih,
               const float* __restrict__ b_hh,
               const float* __restrict__ W_lin,
               const float* __restrict__ b_lin,
               float* __restrict__ out)
{
    __shared__ float xs[TSZ][NB];                         // x^T [t][n]   (8 KB)
    __shared__ __align__(16) float gl[4][NB * GNS];       // [w][n*260+u*4+g]
    __shared__ __align__(16) _Float16 hlds[2][16][KPAD];  // aug-h^T dbuf (4.5 KB)

    const int tid = threadIdx.x;
    const int w   = tid >> 6;        // wave id 0..3 -> unit group [16w,16w+16)
    const int ln  = tid & 63;        // lane
    const int n   = ln & 15;         // MFMA column
    const int q   = ln >> 4;         // quad
    const int na  = ln >> 4;         // activation batch   (0..3)
    const int ua  = ln & 15;         // activation unit offset (0..15)
    const int b0  = blockIdx.x * NB;

    // --- stage x transposed: global [b][t] -> LDS [t][b] (coalesced) ---
    const float* xg = x + (size_t)b0 * TSZ;
    for (int i = tid; i < NB * TSZ; i += 256)
        xs[i & (TSZ - 1)][i >> 9] = xg[i];
    // --- init h buffers: zero except k==50 slot = 1.0 (both buffers) ---
    for (int i = tid; i < 2 * 16 * KPAD; i += 256)
        ((_Float16*)hlds)[i] = (i % KPAD == 50) ? (_Float16)1.0f : (_Float16)0.0f;

    // --- A fragments: lane holds A[m=16w+n][k=kt*32+q*8+j], augmented:
    //     k<50 -> W_hh ; k==50 -> b_ih+b_hh ; k==51 -> W_ih ; else 0.
    const int uA = 16 * w + n;
    half8 af[4][2];
#pragma unroll
    for (int g = 0; g < 4; ++g) {
        const int row = g * HSZ + uA;
        const bool rok = (uA < HSZ);
#pragma unroll
        for (int kt = 0; kt < 2; ++kt) {
#pragma unroll
            for (int j = 0; j < 8; ++j) {
                const int k = kt * 32 + q * 8 + j;
                float v = 0.0f;
                if (rok) {
                    if (k < HSZ)      v = W_hh[row * HSZ + k];
                    else if (k == 50) v = b_ih[row] + b_hh[row];
                    else if (k == 51) v = W_ih[row];
                }
                af[g][kt][j] = (_Float16)v;
            }
        }
    }

    float c = 0.0f;                  // lane-local cell state (batch na, unit 16w+ua)
    __syncthreads();                 // xs + hlds base fill ready
    if (tid < NB)                    // x_0 into buffer 0's aug slot
        hlds[0][tid][51] = (_Float16)xs[0][tid];
    __syncthreads();

    const floatx4 zero4 = {0.0f, 0.0f, 0.0f, 0.0f};
    const int kdst = 16 * w + ua;    // this lane's h destination row in k
    const bool hwr = (kdst != 50) && (kdst != 51);   // don't clobber aug slots

#pragma unroll 2
    for (int t = 0; t < TSZ; ++t) {
        const int rb = t & 1, wb = rb ^ 1;

        // B fragments: hlds[rb][n][k-contiguous] (cols 4..15 are dummy batches)
        const half8 bf0 = *(const half8*)&hlds[rb][n][q * 8];
        const half8 bf1 = *(const half8*)&hlds[rb][n][32 + q * 8];

        // Next step's x into the write buffer's aug slot (wave 0, 4 lanes).
        if (w == 0 && ua == 15)
            hlds[wb][na][51] = (_Float16)xs[(t + 1) & (TSZ - 1)][na];

        floatx4 acc[4];
#pragma unroll
        for (int g = 0; g < 4; ++g) {
            acc[g] = __builtin_amdgcn_mfma_f32_16x16x32_f16(af[g][0], bf0, zero4,  0, 0, 0);
            acc[g] = __builtin_amdgcn_mfma_f32_16x16x32_f16(af[g][1], bf1, acc[g], 0, 0, 0);
        }

        // Wave-private repack, gate-interleaved: lane (q,n<4) owns all 4 gates
        // of units 4q+r -> b128 {i,f,g,o} to gl[w][n*260 + (4q+r)*4].
        if (n < NB) {
#pragma unroll
            for (int r = 0; r < 4; ++r) {
                const floatx4 v = {acc[0][r], acc[1][r], acc[2][r], acc[3][r]};
                *(floatx4*)&gl[w][n * GNS + (4 * q + r) * 4] = v;
            }
        }
        // Consumer: ONE b128 read gives this lane's 4 gate preacts.
        const floatx4 pre = *(const floatx4*)&gl[w][na * GNS + ua * 4];

        const float si = fast_sig (pre[0]);
        const float sf = fast_sig (pre[1]);
        const float sg = fast_tanh(pre[2]);
        const float so = fast_sig (pre[3]);
        c = fmaf(sf, c, si * sg);
        const float h = so * fast_tanh(c);

        if (hwr)
            hlds[wb][na][kdst] = (_Float16)h;   // pad units write h==0: fine
        __syncthreads();             // h(t) visible for next step's B-read
    }

    // --- epilogue: out[b0+n'] = b_lin + sum_u h_T[u]*W_lin[u]; TSZ even -> buf 0
    if (w == 0 && ln < NB) {
        float acc = b_lin[0];
        for (int u = 0; u < HSZ; ++u)
            acc = fmaf((float)hlds[0][ln][u], W_lin[u], acc);
        out[(size_t)b0 + ln] = acc;
    }
}

extern "C" void kernel_launch(void* const* d_in, const int* in_sizes, int n_in,
                              void* d_out, int out_size, void* d_ws, size_t ws_size,
                              hipStream_t stream) {
    const float* x     = (const float*)d_in[0];
    const float* W_ih  = (const float*)d_in[1];
    const float* W_hh  = (const float*)d_in[2];
    const float* b_ih  = (const float*)d_in[3];
    const float* b_hh  = (const float*)d_in[4];
    const float* W_lin = (const float*)d_in[5];
    const float* b_lin = (const float*)d_in[6];
    float* outp = (float*)d_out;

    const int B = in_sizes[0] / TSZ;   // 2048 -> 512 workgroups of 4 batches
    hipLaunchKernelGGL(lstm_kaug, dim3(B / NB), dim3(256), 0, stream,
                       x, W_ih, W_hh, b_ih, b_hh, W_lin, b_lin, outp);
}